// Round 10
// baseline (152.757 us; speedup 1.0000x reference)
//
#include <hip/hip_runtime.h>

#define NN 50000
#define NE 1600000
#define DF 64
#define DH 128

#define NBK 782           // buckets of 64 rows: bucket = r >> 6
#define PB_EDGES 16384    // edges per k_part block (1024 thr x 16)
#define CAPF 4096         // per-chunk edge capacity (mean 2046, sd ~45)

// ws layout (bytes):
//   cnt    : int[784]        @ 0         (zeroed each call)
//   queue  : int             @ 3136      (zeroed each call)
//   start  : int[783]        @ 4096
//   cursor : int[783]        @ 8192
//   colc   : ushort[NE]      @ 12288     (3,200,000 B)
//   rloc   : uchar[NE]       @ 3,212,288 (1,600,000 B)
//   xb     : ushort[NN*DF]   @ 4,812,288 (6,400,000 B)
// total 11,212,288 B (proven budget)

typedef __attribute__((ext_vector_type(8))) short bf16x8;
typedef __attribute__((ext_vector_type(4))) float f32x4;

__device__ __forceinline__ unsigned short f2bf(float f) {
    unsigned u = __float_as_uint(f);
    unsigned r = (u + 0x7FFFu + ((u >> 16) & 1u)) >> 16;  // RNE
    return (unsigned short)r;
}
__device__ __forceinline__ float bf2f(unsigned short h) {
    return __uint_as_float((unsigned)h << 16);
}

// ---------- cast x (f32) -> xb (bf16 raw) ----------
__global__ __launch_bounds__(256) void k_cast(const float* __restrict__ x,
                                              ushort* __restrict__ xb) {
    unsigned i = blockIdx.x * 256u + threadIdx.x;
    if (i >= NN * DF / 4) return;
    float4 v = ((const float4*)x)[i];
    ushort4 o;
    o.x = f2bf(v.x); o.y = f2bf(v.y); o.z = f2bf(v.z); o.w = f2bf(v.w);
    ((ushort4*)xb)[i] = o;
}

// ---------- bucket histogram ----------
__global__ __launch_bounds__(256) void k_hist(const int* __restrict__ ei,
                                              int* __restrict__ cnt) {
    __shared__ int h[784];
    for (int i = threadIdx.x; i < 784; i += 256) h[i] = 0;
    __syncthreads();
    for (unsigned e = blockIdx.x * 256u + threadIdx.x; e < NE; e += 512u * 256u) {
        int r = ei[e];
        int c = ei[NE + e];
        if (r != c) atomicAdd(&h[r >> 6], 1);
    }
    __syncthreads();
    for (int i = threadIdx.x; i < NBK; i += 256)
        if (h[i]) atomicAdd(&cnt[i], h[i]);
}

// ---------- exclusive scan of NBK bucket counts (1 wave) ----------
__global__ __launch_bounds__(64) void k_scan2(const int* __restrict__ cnt,
                                              int* __restrict__ start,
                                              int* __restrict__ cursor) {
    const int lane = threadIdx.x;
    int run = 0;
    for (int base = 0; base < 832; base += 64) {
        int i = base + lane;
        int v = (i < NBK) ? cnt[i] : 0;
        int s = v;
#pragma unroll
        for (int off = 1; off < 64; off <<= 1) {
            int y = __shfl_up(s, off, 64);
            if (lane >= off) s += y;
        }
        int excl = run + s - v;
        if (i < NBK + 1) { start[i] = excl; cursor[i] = excl; }
        run += __shfl(s, 63, 64);
    }
}

// ---------- partition: 16384 edges/block with block-level reservation ----------
__global__ __launch_bounds__(1024) void k_part(const int* __restrict__ ei,
                                               int* __restrict__ cursor,
                                               ushort* __restrict__ colc,
                                               unsigned char* __restrict__ rloc) {
    __shared__ int lhist[784];
    __shared__ int lbase[784];
    const int tid = threadIdx.x;
    const int e0 = blockIdx.x * PB_EDGES;

    for (int i = tid; i < 784; i += 1024) lhist[i] = 0;
    __syncthreads();

    int rr[16], cc[16], bk[16], val[16];
#pragma unroll
    for (int k = 0; k < 16; ++k) {
        int e = e0 + k * 1024 + tid;
        int ok = (e < NE);
        int idx = ok ? e : 0;
        int r = ei[idx];
        int c = ei[NE + idx];
        int v = ok && (r != c);
        rr[k] = r; cc[k] = c; bk[k] = r >> 6; val[k] = v;
        if (v) atomicAdd(&lhist[bk[k]], 1);
    }
    __syncthreads();

    for (int b = tid; b < NBK; b += 1024) {
        int n = lhist[b];
        lbase[b] = (n > 0) ? atomicAdd(&cursor[b], n) : 0;
    }
    __syncthreads();
    for (int i = tid; i < 784; i += 1024) lhist[i] = 0;  // reuse as local cursor
    __syncthreads();

#pragma unroll
    for (int k = 0; k < 16; ++k) {
        if (val[k]) {
            int off = atomicAdd(&lhist[bk[k]], 1);
            int pos = lbase[bk[k]] + off;
            colc[pos] = (unsigned short)cc[k];
            rloc[pos] = (unsigned char)(rr[k] & 63);
        }
    }
}

// ---------- fused aggregate + MLP: persistent blocks, dynamic bucket queue ----------
// per bucket (64 rows): counting-sort edges by row -> register gather-sum ->
// in_s bf16 -> MFMA MLP (layouts proven round 9) -> final out.
#define IN_LD 72      // 144 B rows (16B-aligned)
#define W1_LD 72
#define W2_LD 136     // 272 B rows
#define H_LD 136

__global__ __launch_bounds__(1024) void k_fused(const float* __restrict__ x,
                                                const ushort* __restrict__ xb,
                                                const int* __restrict__ start,
                                                const ushort* __restrict__ colc,
                                                const unsigned char* __restrict__ rloc,
                                                const float* __restrict__ w1,
                                                const float* __restrict__ b1,
                                                const float* __restrict__ w2,
                                                const float* __restrict__ b2,
                                                const float* __restrict__ eps,
                                                int* __restrict__ queue,
                                                float* __restrict__ out) {
    __shared__ int hist[64];
    __shared__ int rs[65];
    __shared__ int curs[64];
    __shared__ int s_b;
    __shared__ ushort scol[CAPF];             //  8,192 B
    __shared__ ushort in_s[64 * IN_LD];       //  9,216 B
    __shared__ ushort w1t_s[128 * W1_LD];     // 18,432 B  w1t[j][k]
    __shared__ ushort w2t_s[64 * W2_LD];      // 17,408 B  w2t[c][j]
    __shared__ ushort h_s[4 * 16 * H_LD];     // 17,408 B  per-tile [16][136]
    // total ~71.4 KB -> 2 blocks/CU

    const int tid = threadIdx.x;
    const int w = tid >> 6;
    const int lane = tid & 63;
    const int quad = lane >> 4;
    const int r16 = lane & 15;

    // ---- stage weights once per block ----
#pragma unroll
    for (int t = 0; t < 2; ++t) {
        int i4 = t * 1024 + tid;             // 2048 float4 of w1 (64x128)
        float4 v = ((const float4*)w1)[i4];
        int idx = i4 * 4;
        int k = idx >> 7, j = idx & 127;
        w1t_s[(j + 0) * W1_LD + k] = f2bf(v.x);
        w1t_s[(j + 1) * W1_LD + k] = f2bf(v.y);
        w1t_s[(j + 2) * W1_LD + k] = f2bf(v.z);
        w1t_s[(j + 3) * W1_LD + k] = f2bf(v.w);
    }
#pragma unroll
    for (int t = 0; t < 2; ++t) {
        int i4 = t * 1024 + tid;             // 2048 float4 of w2 (128x64)
        float4 v = ((const float4*)w2)[i4];
        int idx = i4 * 4;
        int j = idx >> 6, c = idx & 63;
        w2t_s[(c + 0) * W2_LD + j] = f2bf(v.x);
        w2t_s[(c + 1) * W2_LD + j] = f2bf(v.y);
        w2t_s[(c + 2) * W2_LD + j] = f2bf(v.z);
        w2t_s[(c + 3) * W2_LD + j] = f2bf(v.w);
    }
    const float ev = 1.0f + eps[0];

    for (;;) {
        if (tid == 0) s_b = atomicAdd(queue, 1);
        __syncthreads();
        const int b = s_b;
        if (b >= NBK) break;
        const int s = start[b], e = start[b + 1];
        const int row0 = b << 6;

        // ---- aggregate: counting-sort + register accumulation ----
        float a0 = 0.f, a1 = 0.f, a2 = 0.f, a3 = 0.f;
        for (int cs0 = s; cs0 < e; cs0 += CAPF) {
            const int m = min(e - cs0, CAPF);

            if (tid < 64) hist[tid] = 0;
            __syncthreads();

            for (int i = tid; i < m; i += 1024)
                atomicAdd(&hist[rloc[cs0 + i]], 1);
            __syncthreads();

            if (tid < 64) {
                int v = hist[tid];
                int p = v;
#pragma unroll
                for (int off = 1; off < 64; off <<= 1) {
                    int y = __shfl_up(p, off, 64);
                    if (tid >= off) p += y;
                }
                rs[tid] = p - v;
                curs[tid] = p - v;
                if (tid == 63) rs[64] = p;
            }
            __syncthreads();

            for (int i = tid; i < m; i += 1024) {
                int r = rloc[cs0 + i];
                int p = atomicAdd(&curs[r], 1);
                scol[p] = colc[cs0 + i];
            }
            __syncthreads();

            // wave w owns rows w, w+16, w+32, w+48 (8-deep gather pipeline)
#pragma unroll
            for (int jp = 0; jp < 4; ++jp) {
                const int rl = w + jp * 16;
                int k = rs[rl];
                const int kend = rs[rl + 1];
                float acc = 0.f;
                for (; k + 8 <= kend; k += 8) {
                    int c0 = scol[k],     c1 = scol[k + 1], c2 = scol[k + 2], c3 = scol[k + 3];
                    int c4 = scol[k + 4], c5 = scol[k + 5], c6 = scol[k + 6], c7 = scol[k + 7];
                    float v0 = bf2f(xb[(size_t)c0 * DF + lane]);
                    float v1 = bf2f(xb[(size_t)c1 * DF + lane]);
                    float v2 = bf2f(xb[(size_t)c2 * DF + lane]);
                    float v3 = bf2f(xb[(size_t)c3 * DF + lane]);
                    float v4 = bf2f(xb[(size_t)c4 * DF + lane]);
                    float v5 = bf2f(xb[(size_t)c5 * DF + lane]);
                    float v6 = bf2f(xb[(size_t)c6 * DF + lane]);
                    float v7 = bf2f(xb[(size_t)c7 * DF + lane]);
                    acc += v0; acc += v1; acc += v2; acc += v3;
                    acc += v4; acc += v5; acc += v6; acc += v7;
                }
                for (; k + 4 <= kend; k += 4) {
                    int c0 = scol[k], c1 = scol[k + 1], c2 = scol[k + 2], c3 = scol[k + 3];
                    float v0 = bf2f(xb[(size_t)c0 * DF + lane]);
                    float v1 = bf2f(xb[(size_t)c1 * DF + lane]);
                    float v2 = bf2f(xb[(size_t)c2 * DF + lane]);
                    float v3 = bf2f(xb[(size_t)c3 * DF + lane]);
                    acc += v0; acc += v1; acc += v2; acc += v3;
                }
                for (; k < kend; ++k) acc += bf2f(xb[(size_t)scol[k] * DF + lane]);
                if (jp == 0) a0 += acc; else if (jp == 1) a1 += acc;
                else if (jp == 2) a2 += acc; else a3 += acc;
            }
            __syncthreads();   // before next chunk rewrites hist/scol
        }

        // ---- epilogue: in = (1+eps)*x + agg, bf16 into in_s ----
#pragma unroll
        for (int jp = 0; jp < 4; ++jp) {
            const int rl = w + jp * 16;
            const int row = row0 + rl;
            float acc = (jp == 0) ? a0 : (jp == 1) ? a1 : (jp == 2) ? a2 : a3;
            float xv = (row < NN) ? x[(size_t)row * DF + lane] : 0.f;
            in_s[rl * IN_LD + lane] = f2bf(ev * xv + acc);
        }
        __syncthreads();

        // ---- MLP layer 1: tile t = w>>2 (16 rows), sub = w&3 handles 2 n-tiles ----
        {
            const int t = w >> 2, sub = w & 3;
            const ushort* inrow = in_s + (t * 16 + r16) * IN_LD + quad * 8;
            bf16x8 aA = *(const bf16x8*)(inrow);
            bf16x8 aB = *(const bf16x8*)(inrow + 32);
            ushort* ht = h_s + t * 16 * H_LD;
#pragma unroll
            for (int q = 0; q < 2; ++q) {
                const int nt = sub * 2 + q;
                const ushort* bp = w1t_s + (nt * 16 + r16) * W1_LD + quad * 8;
                bf16x8 bA = *(const bf16x8*)(bp);
                bf16x8 bB = *(const bf16x8*)(bp + 32);
                f32x4 acc = {0.f, 0.f, 0.f, 0.f};
                acc = __builtin_amdgcn_mfma_f32_16x16x32_bf16(aA, bA, acc, 0, 0, 0);
                acc = __builtin_amdgcn_mfma_f32_16x16x32_bf16(aB, bB, acc, 0, 0, 0);
                float bias = b1[nt * 16 + r16];
#pragma unroll
                for (int reg = 0; reg < 4; ++reg) {
                    float hv = fmaxf(acc[reg] + bias, 0.f);
                    ht[(quad * 4 + reg) * H_LD + nt * 16 + r16] = f2bf(hv);
                }
            }
        }
        __syncthreads();

        // ---- MLP layer 2: wave computes cols sub*16..+15 of its tile ----
        {
            const int t = w >> 2, sub = w & 3;
            const ushort* ht = h_s + t * 16 * H_LD;
            f32x4 acc2 = {0.f, 0.f, 0.f, 0.f};
#pragma unroll
            for (int ks = 0; ks < 4; ++ks) {
                bf16x8 a2 = *(const bf16x8*)(ht + r16 * H_LD + quad * 8 + ks * 32);
                bf16x8 b2f = *(const bf16x8*)(w2t_s + (sub * 16 + r16) * W2_LD + quad * 8 + ks * 32);
                acc2 = __builtin_amdgcn_mfma_f32_16x16x32_bf16(a2, b2f, acc2, 0, 0, 0);
            }
            float bias2 = b2[sub * 16 + r16];
#pragma unroll
            for (int reg = 0; reg < 4; ++reg) {
                int mrow = row0 + t * 16 + quad * 4 + reg;
                if (mrow < NN) out[(size_t)mrow * DF + sub * 16 + r16] = acc2[reg] + bias2;
            }
        }
        // next queue-pop __syncthreads separates bucket iterations
    }
}

extern "C" void kernel_launch(void* const* d_in, const int* in_sizes, int n_in,
                              void* d_out, int out_size, void* d_ws, size_t ws_size,
                              hipStream_t stream) {
    const float* x   = (const float*)d_in[0];
    const int*   ei  = (const int*)d_in[1];
    const float* w1  = (const float*)d_in[2];
    const float* b1  = (const float*)d_in[3];
    const float* w2  = (const float*)d_in[4];
    const float* b2  = (const float*)d_in[5];
    const float* eps = (const float*)d_in[6];
    float* out = (float*)d_out;

    char* ws = (char*)d_ws;
    int*           cnt    = (int*)(ws + 0);
    int*           queue  = (int*)(ws + 3136);
    int*           start  = (int*)(ws + 4096);
    int*           cursor = (int*)(ws + 8192);
    ushort*        colc   = (ushort*)(ws + 12288);
    unsigned char* rloc   = (unsigned char*)(ws + 3212288);
    ushort*        xb     = (ushort*)(ws + 4812288);

    hipMemsetAsync(ws, 0, 4096, stream);   // cnt + queue

    k_cast<<<NN * DF / 4 / 256, 256, 0, stream>>>(x, xb);
    k_hist<<<512, 256, 0, stream>>>(ei, cnt);
    k_scan2<<<1, 64, 0, stream>>>(cnt, start, cursor);
    k_part<<<(NE + PB_EDGES - 1) / PB_EDGES, 1024, 0, stream>>>(ei, cursor, colc, rloc);
    k_fused<<<512, 1024, 0, stream>>>(x, xb, start, colc, rloc, w1, b1, w2, b2, eps, queue, out);
}

// Round 11
// 122.183 us; speedup vs baseline: 1.2502x; 1.2502x over previous
//
#include <hip/hip_runtime.h>

#define NN 50000
#define NE 1600000
#define DF 64
#define DH 128

#define NBK 782           // buckets of 64 rows: bucket = r >> 6
#define PB_EDGES 8192     // edges per k_part block (1024 thr x 8) -> 196 blocks
#define CAPF 4096         // per-chunk edge capacity in k_agg (mean 2046, sd ~45)

// ws layout (bytes):
//   cnt    : int[784]        @ 0         (zeroed each call)
//   start  : int[783]        @ 4096
//   cursor : int[783]        @ 8192
//   colc   : ushort[NE]      @ 12288     (3,200,000 B)
//   rloc   : uchar[NE]       @ 3,212,288 (1,600,000 B)
//   xb     : ushort[NN*DF]   @ 4,812,288 (6,400,000 B)
// total 11,212,288 B (proven budget)

typedef __attribute__((ext_vector_type(8))) short bf16x8;
typedef __attribute__((ext_vector_type(4))) float f32x4;

__device__ __forceinline__ unsigned short f2bf(float f) {
    unsigned u = __float_as_uint(f);
    unsigned r = (u + 0x7FFFu + ((u >> 16) & 1u)) >> 16;  // RNE
    return (unsigned short)r;
}
__device__ __forceinline__ float bf2f(unsigned short h) {
    return __uint_as_float((unsigned)h << 16);
}

// ---------- cast x (f32) -> xb (bf16 raw) ----------
__global__ __launch_bounds__(256) void k_cast(const float* __restrict__ x,
                                              ushort* __restrict__ xb) {
    unsigned i = blockIdx.x * 256u + threadIdx.x;
    if (i >= NN * DF / 4) return;
    float4 v = ((const float4*)x)[i];
    ushort4 o;
    o.x = f2bf(v.x); o.y = f2bf(v.y); o.z = f2bf(v.z); o.w = f2bf(v.w);
    ((ushort4*)xb)[i] = o;
}

// ---------- bucket histogram (LDS-staged, native int atomics) ----------
__global__ __launch_bounds__(256) void k_hist(const int* __restrict__ ei,
                                              int* __restrict__ cnt) {
    __shared__ int h[784];
    for (int i = threadIdx.x; i < 784; i += 256) h[i] = 0;
    __syncthreads();
    for (unsigned e = blockIdx.x * 256u + threadIdx.x; e < NE; e += 512u * 256u) {
        int r = ei[e];
        int c = ei[NE + e];
        if (r != c) atomicAdd(&h[r >> 6], 1);
    }
    __syncthreads();
    for (int i = threadIdx.x; i < NBK; i += 256)
        if (h[i]) atomicAdd(&cnt[i], h[i]);
}

// ---------- exclusive scan of NBK bucket counts (1 wave) ----------
__global__ __launch_bounds__(64) void k_scan2(const int* __restrict__ cnt,
                                              int* __restrict__ start,
                                              int* __restrict__ cursor) {
    const int lane = threadIdx.x;
    int run = 0;
    for (int base = 0; base < 832; base += 64) {
        int i = base + lane;
        int v = (i < NBK) ? cnt[i] : 0;
        int s = v;
#pragma unroll
        for (int off = 1; off < 64; off <<= 1) {
            int y = __shfl_up(s, off, 64);
            if (lane >= off) s += y;
        }
        int excl = run + s - v;
        if (i < NBK + 1) { start[i] = excl; cursor[i] = excl; }
        run += __shfl(s, 63, 64);
    }
}

// ---------- partition: 8192 edges/block with block-level reservation ----------
__global__ __launch_bounds__(1024) void k_part(const int* __restrict__ ei,
                                               int* __restrict__ cursor,
                                               ushort* __restrict__ colc,
                                               unsigned char* __restrict__ rloc) {
    __shared__ int lhist[784];
    __shared__ int lbase[784];
    const int tid = threadIdx.x;
    const int e0 = blockIdx.x * PB_EDGES;

    for (int i = tid; i < 784; i += 1024) lhist[i] = 0;
    __syncthreads();

    int rr[8], cc[8], bk[8], val[8];
#pragma unroll
    for (int k = 0; k < 8; ++k) {
        int e = e0 + k * 1024 + tid;
        int ok = (e < NE);
        int idx = ok ? e : 0;
        int r = ei[idx];
        int c = ei[NE + idx];
        int v = ok && (r != c);
        rr[k] = r; cc[k] = c; bk[k] = r >> 6; val[k] = v;
        if (v) atomicAdd(&lhist[bk[k]], 1);
    }
    __syncthreads();

    for (int b = tid; b < NBK; b += 1024) {
        int n = lhist[b];
        lbase[b] = (n > 0) ? atomicAdd(&cursor[b], n) : 0;
    }
    __syncthreads();
    for (int i = tid; i < 784; i += 1024) lhist[i] = 0;  // reuse as local cursor
    __syncthreads();

#pragma unroll
    for (int k = 0; k < 8; ++k) {
        if (val[k]) {
            int off = atomicAdd(&lhist[bk[k]], 1);
            int pos = lbase[bk[k]] + off;
            colc[pos] = (unsigned short)cc[k];
            rloc[pos] = (unsigned char)(rr[k] & 63);
        }
    }
}

// ---------- aggregate: one block per 64-row bucket; LDS counting-sort by row,
// register accumulation (proven inner loops; finer blocks for HW load balance) ----------
__global__ __launch_bounds__(1024) void k_agg(const float* __restrict__ x,
                                              const ushort* __restrict__ xb,
                                              const int* __restrict__ start,
                                              const ushort* __restrict__ colc,
                                              const unsigned char* __restrict__ rloc,
                                              const float* __restrict__ eps,
                                              float* __restrict__ out) {
    __shared__ int hist[64];
    __shared__ int rs[65];
    __shared__ int curs[64];
    __shared__ ushort scol[CAPF];    // 8 KB

    const int tid = threadIdx.x;
    const int b = blockIdx.x;
    const int w = tid >> 6;         // wave 0..15
    const int f = tid & 63;         // feature lane
    const int s = start[b], e = start[b + 1];

    float a0 = 0.f, a1 = 0.f, a2 = 0.f, a3 = 0.f;

    for (int cs0 = s; cs0 < e; cs0 += CAPF) {
        const int m = min(e - cs0, CAPF);

        if (tid < 64) hist[tid] = 0;
        __syncthreads();

        for (int i = tid; i < m; i += 1024)
            atomicAdd(&hist[rloc[cs0 + i]], 1);
        __syncthreads();

        if (tid < 64) {
            int v = hist[tid];
            int p = v;
#pragma unroll
            for (int off = 1; off < 64; off <<= 1) {
                int y = __shfl_up(p, off, 64);
                if (tid >= off) p += y;
            }
            rs[tid] = p - v;
            curs[tid] = p - v;
            if (tid == 63) rs[64] = p;
        }
        __syncthreads();

        for (int i = tid; i < m; i += 1024) {
            int r = rloc[cs0 + i];
            int p = atomicAdd(&curs[r], 1);
            scol[p] = colc[cs0 + i];
        }
        __syncthreads();

        // wave w owns rows w, w+16, w+32, w+48 (8-deep gather pipeline)
#pragma unroll
        for (int jp = 0; jp < 4; ++jp) {
            const int rl = w + jp * 16;
            int k = rs[rl];
            const int kend = rs[rl + 1];
            float acc = 0.f;
            for (; k + 8 <= kend; k += 8) {
                int c0 = scol[k],     c1 = scol[k + 1], c2 = scol[k + 2], c3 = scol[k + 3];
                int c4 = scol[k + 4], c5 = scol[k + 5], c6 = scol[k + 6], c7 = scol[k + 7];
                float v0 = bf2f(xb[(size_t)c0 * DF + f]);
                float v1 = bf2f(xb[(size_t)c1 * DF + f]);
                float v2 = bf2f(xb[(size_t)c2 * DF + f]);
                float v3 = bf2f(xb[(size_t)c3 * DF + f]);
                float v4 = bf2f(xb[(size_t)c4 * DF + f]);
                float v5 = bf2f(xb[(size_t)c5 * DF + f]);
                float v6 = bf2f(xb[(size_t)c6 * DF + f]);
                float v7 = bf2f(xb[(size_t)c7 * DF + f]);
                acc += v0; acc += v1; acc += v2; acc += v3;
                acc += v4; acc += v5; acc += v6; acc += v7;
            }
            for (; k + 4 <= kend; k += 4) {
                int c0 = scol[k], c1 = scol[k + 1], c2 = scol[k + 2], c3 = scol[k + 3];
                float v0 = bf2f(xb[(size_t)c0 * DF + f]);
                float v1 = bf2f(xb[(size_t)c1 * DF + f]);
                float v2 = bf2f(xb[(size_t)c2 * DF + f]);
                float v3 = bf2f(xb[(size_t)c3 * DF + f]);
                acc += v0; acc += v1; acc += v2; acc += v3;
            }
            for (; k < kend; ++k) acc += bf2f(xb[(size_t)scol[k] * DF + f]);
            if (jp == 0) a0 += acc; else if (jp == 1) a1 += acc;
            else if (jp == 2) a2 += acc; else a3 += acc;
        }
        __syncthreads();
    }

    const float ev = 1.0f + eps[0];
    const int row0 = b << 6;
#pragma unroll
    for (int jp = 0; jp < 4; ++jp) {
        int row = row0 + w + jp * 16;
        if (row < NN) {
            float acc = (jp == 0) ? a0 : (jp == 1) ? a1 : (jp == 2) ? a2 : a3;
            out[(size_t)row * DF + f] = ev * x[(size_t)row * DF + f] + acc;
        }
    }
}

// ---------- MFMA MLP (proven round 9, unchanged) ----------
#define IN_LD 72
#define W1_LD 72
#define W2_LD 136
#define H_LD 136

__global__ __launch_bounds__(256) void k_mlp(float* io,
                                             const float* __restrict__ w1,
                                             const float* __restrict__ b1,
                                             const float* __restrict__ w2,
                                             const float* __restrict__ b2) {
    __shared__ ushort in_s[64 * IN_LD];
    __shared__ ushort w1t_s[128 * W1_LD];
    __shared__ ushort w2t_s[64 * W2_LD];
    __shared__ ushort h_s[4 * 16 * H_LD];

    const int tid = threadIdx.x;
    const int m0 = blockIdx.x * 64;
    const int w = tid >> 6;
    const int lane = tid & 63;
    const int quad = lane >> 4;
    const int r16 = lane & 15;

#pragma unroll
    for (int t = 0; t < 8; ++t) {
        int i4 = t * 256 + tid;
        float4 v = ((const float4*)w1)[i4];
        int idx = i4 * 4;
        int k = idx >> 7, j = idx & 127;
        w1t_s[(j + 0) * W1_LD + k] = f2bf(v.x);
        w1t_s[(j + 1) * W1_LD + k] = f2bf(v.y);
        w1t_s[(j + 2) * W1_LD + k] = f2bf(v.z);
        w1t_s[(j + 3) * W1_LD + k] = f2bf(v.w);
    }
#pragma unroll
    for (int t = 0; t < 8; ++t) {
        int i4 = t * 256 + tid;
        float4 v = ((const float4*)w2)[i4];
        int idx = i4 * 4;
        int j = idx >> 6, c = idx & 63;
        w2t_s[(c + 0) * W2_LD + j] = f2bf(v.x);
        w2t_s[(c + 1) * W2_LD + j] = f2bf(v.y);
        w2t_s[(c + 2) * W2_LD + j] = f2bf(v.z);
        w2t_s[(c + 3) * W2_LD + j] = f2bf(v.w);
    }
#pragma unroll
    for (int t = 0; t < 4; ++t) {
        int i4 = t * 256 + tid;
        int row = i4 >> 4, fq = i4 & 15;
        float4 v = make_float4(0.f, 0.f, 0.f, 0.f);
        if (m0 + row < NN) v = ((const float4*)io)[(size_t)(m0 + row) * 16 + fq];
        ushort4 o;
        o.x = f2bf(v.x); o.y = f2bf(v.y); o.z = f2bf(v.z); o.w = f2bf(v.w);
        *(ushort4*)&in_s[row * IN_LD + fq * 4] = o;
    }
    __syncthreads();

    const ushort* inrow = in_s + (w * 16 + r16) * IN_LD + quad * 8;
    bf16x8 aA = *(const bf16x8*)(inrow);
    bf16x8 aB = *(const bf16x8*)(inrow + 32);

    ushort* hw = h_s + w * 16 * H_LD;

#pragma unroll
    for (int nt = 0; nt < 8; ++nt) {
        const ushort* bp = w1t_s + (nt * 16 + r16) * W1_LD + quad * 8;
        bf16x8 bA = *(const bf16x8*)(bp);
        bf16x8 bB = *(const bf16x8*)(bp + 32);
        f32x4 acc = {0.f, 0.f, 0.f, 0.f};
        acc = __builtin_amdgcn_mfma_f32_16x16x32_bf16(aA, bA, acc, 0, 0, 0);
        acc = __builtin_amdgcn_mfma_f32_16x16x32_bf16(aB, bB, acc, 0, 0, 0);
        float bias = b1[nt * 16 + r16];
#pragma unroll
        for (int reg = 0; reg < 4; ++reg) {
            float hv = fmaxf(acc[reg] + bias, 0.f);
            hw[(quad * 4 + reg) * H_LD + nt * 16 + r16] = f2bf(hv);
        }
    }

    f32x4 acc2[4];
#pragma unroll
    for (int ct = 0; ct < 4; ++ct) acc2[ct] = (f32x4){0.f, 0.f, 0.f, 0.f};
#pragma unroll
    for (int ks = 0; ks < 4; ++ks) {
        bf16x8 a2 = *(const bf16x8*)(hw + r16 * H_LD + quad * 8 + ks * 32);
#pragma unroll
        for (int ct = 0; ct < 4; ++ct) {
            bf16x8 b2f = *(const bf16x8*)(w2t_s + (ct * 16 + r16) * W2_LD + quad * 8 + ks * 32);
            acc2[ct] = __builtin_amdgcn_mfma_f32_16x16x32_bf16(a2, b2f, acc2[ct], 0, 0, 0);
        }
    }
#pragma unroll
    for (int ct = 0; ct < 4; ++ct) {
        int c = ct * 16 + r16;
        float bias = b2[c];
#pragma unroll
        for (int reg = 0; reg < 4; ++reg) {
            int m = m0 + w * 16 + quad * 4 + reg;
            if (m < NN) io[(size_t)m * DF + c] = acc2[ct][reg] + bias;
        }
    }
}

extern "C" void kernel_launch(void* const* d_in, const int* in_sizes, int n_in,
                              void* d_out, int out_size, void* d_ws, size_t ws_size,
                              hipStream_t stream) {
    const float* x   = (const float*)d_in[0];
    const int*   ei  = (const int*)d_in[1];
    const float* w1  = (const float*)d_in[2];
    const float* b1  = (const float*)d_in[3];
    const float* w2  = (const float*)d_in[4];
    const float* b2  = (const float*)d_in[5];
    const float* eps = (const float*)d_in[6];
    float* out = (float*)d_out;

    char* ws = (char*)d_ws;
    int*           cnt    = (int*)(ws + 0);
    int*           start  = (int*)(ws + 4096);
    int*           cursor = (int*)(ws + 8192);
    ushort*        colc   = (ushort*)(ws + 12288);
    unsigned char* rloc   = (unsigned char*)(ws + 3212288);
    ushort*        xb     = (ushort*)(ws + 4812288);

    hipMemsetAsync(cnt, 0, 4096, stream);

    k_cast<<<NN * DF / 4 / 256, 256, 0, stream>>>(x, xb);
    k_hist<<<512, 256, 0, stream>>>(ei, cnt);
    k_scan2<<<1, 64, 0, stream>>>(cnt, start, cursor);
    k_part<<<(NE + PB_EDGES - 1) / PB_EDGES, 1024, 0, stream>>>(ei, cursor, colc, rloc);
    k_agg<<<NBK, 1024, 0, stream>>>(x, xb, start, colc, rloc, eps, out);
    k_mlp<<<(NN + 63) / 64, 256, 0, stream>>>(out, w1, b1, w2, b2);
}

// Round 12
// 118.613 us; speedup vs baseline: 1.2879x; 1.0301x over previous
//
#include <hip/hip_runtime.h>

#define NN 50000
#define NE 1600000
#define DF 64
#define DH 128

#define NBK 782           // buckets of 64 rows: bucket = r >> 6
#define PB_EDGES 8192     // edges per k_part block (1024 thr x 8) -> 196 blocks
#define CAPF 4096         // per-chunk edge capacity in k_agg (mean 2046, sd ~45)

// ws layout (bytes):
//   cnt    : int[784]        @ 0         (zeroed by k_cast block 0 each call)
//   start  : int[783]        @ 4096
//   cursor : int[783]        @ 8192
//   colc   : ushort[NE]      @ 12288     (3,200,000 B)
//   rloc   : uchar[NE]       @ 3,212,288 (1,600,000 B)
//   xb     : ushort[NN*DF]   @ 4,812,288 (6,400,000 B)
// total 11,212,288 B (proven budget)

typedef __attribute__((ext_vector_type(8))) short bf16x8;
typedef __attribute__((ext_vector_type(4))) float f32x4;

__device__ __forceinline__ unsigned short f2bf(float f) {
    unsigned u = __float_as_uint(f);
    unsigned r = (u + 0x7FFFu + ((u >> 16) & 1u)) >> 16;  // RNE
    return (unsigned short)r;
}
__device__ __forceinline__ float bf2f(unsigned short h) {
    return __uint_as_float((unsigned)h << 16);
}

// ---------- cast x (f32) -> xb (bf16 raw); block 0 also zeroes cnt ----------
__global__ __launch_bounds__(256) void k_cast(const float* __restrict__ x,
                                              ushort* __restrict__ xb,
                                              int* __restrict__ cnt) {
    if (blockIdx.x == 0) {
        // zero ws[0..4096): cnt[784] + pad (stream order: done before k_hist)
        ((int4*)cnt)[threadIdx.x] = make_int4(0, 0, 0, 0);
    }
    unsigned i = blockIdx.x * 256u + threadIdx.x;
    if (i >= NN * DF / 4) return;
    float4 v = ((const float4*)x)[i];
    ushort4 o;
    o.x = f2bf(v.x); o.y = f2bf(v.y); o.z = f2bf(v.z); o.w = f2bf(v.w);
    ((ushort4*)xb)[i] = o;
}

// ---------- bucket histogram (LDS-staged, native int atomics) ----------
__global__ __launch_bounds__(256) void k_hist(const int* __restrict__ ei,
                                              int* __restrict__ cnt) {
    __shared__ int h[784];
    for (int i = threadIdx.x; i < 784; i += 256) h[i] = 0;
    __syncthreads();
    for (unsigned e = blockIdx.x * 256u + threadIdx.x; e < NE; e += 512u * 256u) {
        int r = ei[e];
        int c = ei[NE + e];
        if (r != c) atomicAdd(&h[r >> 6], 1);
    }
    __syncthreads();
    for (int i = threadIdx.x; i < NBK; i += 256)
        if (h[i]) atomicAdd(&cnt[i], h[i]);
}

// ---------- exclusive scan of NBK bucket counts (1 wave) ----------
__global__ __launch_bounds__(64) void k_scan2(const int* __restrict__ cnt,
                                              int* __restrict__ start,
                                              int* __restrict__ cursor) {
    const int lane = threadIdx.x;
    int run = 0;
    for (int base = 0; base < 832; base += 64) {
        int i = base + lane;
        int v = (i < NBK) ? cnt[i] : 0;
        int s = v;
#pragma unroll
        for (int off = 1; off < 64; off <<= 1) {
            int y = __shfl_up(s, off, 64);
            if (lane >= off) s += y;
        }
        int excl = run + s - v;
        if (i < NBK + 1) { start[i] = excl; cursor[i] = excl; }
        run += __shfl(s, 63, 64);
    }
}

// ---------- partition: 8192 edges/block with block-level reservation ----------
__global__ __launch_bounds__(1024) void k_part(const int* __restrict__ ei,
                                               int* __restrict__ cursor,
                                               ushort* __restrict__ colc,
                                               unsigned char* __restrict__ rloc) {
    __shared__ int lhist[784];
    __shared__ int lbase[784];
    const int tid = threadIdx.x;
    const int e0 = blockIdx.x * PB_EDGES;

    for (int i = tid; i < 784; i += 1024) lhist[i] = 0;
    __syncthreads();

    int rr[8], cc[8], bk[8], val[8];
#pragma unroll
    for (int k = 0; k < 8; ++k) {
        int e = e0 + k * 1024 + tid;
        int ok = (e < NE);
        int idx = ok ? e : 0;
        int r = ei[idx];
        int c = ei[NE + idx];
        int v = ok && (r != c);
        rr[k] = r; cc[k] = c; bk[k] = r >> 6; val[k] = v;
        if (v) atomicAdd(&lhist[bk[k]], 1);
    }
    __syncthreads();

    for (int b = tid; b < NBK; b += 1024) {
        int n = lhist[b];
        lbase[b] = (n > 0) ? atomicAdd(&cursor[b], n) : 0;
    }
    __syncthreads();
    for (int i = tid; i < 784; i += 1024) lhist[i] = 0;  // reuse as local cursor
    __syncthreads();

#pragma unroll
    for (int k = 0; k < 8; ++k) {
        if (val[k]) {
            int off = atomicAdd(&lhist[bk[k]], 1);
            int pos = lbase[bk[k]] + off;
            colc[pos] = (unsigned short)cc[k];
            rloc[pos] = (unsigned char)(rr[k] & 63);
        }
    }
}

// ---------- aggregate: one block per 64-row bucket; LDS counting-sort by row,
// register accumulation (proven inner loops) ----------
__global__ __launch_bounds__(1024) void k_agg(const float* __restrict__ x,
                                              const ushort* __restrict__ xb,
                                              const int* __restrict__ start,
                                              const ushort* __restrict__ colc,
                                              const unsigned char* __restrict__ rloc,
                                              const float* __restrict__ eps,
                                              float* __restrict__ out) {
    __shared__ int hist[64];
    __shared__ int rs[65];
    __shared__ int curs[64];
    __shared__ ushort scol[CAPF];    // 8 KB

    const int tid = threadIdx.x;
    const int b = blockIdx.x;
    const int w = tid >> 6;         // wave 0..15
    const int f = tid & 63;         // feature lane
    const int s = start[b], e = start[b + 1];

    float a0 = 0.f, a1 = 0.f, a2 = 0.f, a3 = 0.f;

    for (int cs0 = s; cs0 < e; cs0 += CAPF) {
        const int m = min(e - cs0, CAPF);

        if (tid < 64) hist[tid] = 0;
        __syncthreads();

        for (int i = tid; i < m; i += 1024)
            atomicAdd(&hist[rloc[cs0 + i]], 1);
        __syncthreads();

        if (tid < 64) {
            int v = hist[tid];
            int p = v;
#pragma unroll
            for (int off = 1; off < 64; off <<= 1) {
                int y = __shfl_up(p, off, 64);
                if (tid >= off) p += y;
            }
            rs[tid] = p - v;
            curs[tid] = p - v;
            if (tid == 63) rs[64] = p;
        }
        __syncthreads();

        for (int i = tid; i < m; i += 1024) {
            int r = rloc[cs0 + i];
            int p = atomicAdd(&curs[r], 1);
            scol[p] = colc[cs0 + i];
        }
        __syncthreads();

        // wave w owns rows w, w+16, w+32, w+48 (8-deep gather pipeline)
#pragma unroll
        for (int jp = 0; jp < 4; ++jp) {
            const int rl = w + jp * 16;
            int k = rs[rl];
            const int kend = rs[rl + 1];
            float acc = 0.f;
            for (; k + 8 <= kend; k += 8) {
                int c0 = scol[k],     c1 = scol[k + 1], c2 = scol[k + 2], c3 = scol[k + 3];
                int c4 = scol[k + 4], c5 = scol[k + 5], c6 = scol[k + 6], c7 = scol[k + 7];
                float v0 = bf2f(xb[(size_t)c0 * DF + f]);
                float v1 = bf2f(xb[(size_t)c1 * DF + f]);
                float v2 = bf2f(xb[(size_t)c2 * DF + f]);
                float v3 = bf2f(xb[(size_t)c3 * DF + f]);
                float v4 = bf2f(xb[(size_t)c4 * DF + f]);
                float v5 = bf2f(xb[(size_t)c5 * DF + f]);
                float v6 = bf2f(xb[(size_t)c6 * DF + f]);
                float v7 = bf2f(xb[(size_t)c7 * DF + f]);
                acc += v0; acc += v1; acc += v2; acc += v3;
                acc += v4; acc += v5; acc += v6; acc += v7;
            }
            for (; k + 4 <= kend; k += 4) {
                int c0 = scol[k], c1 = scol[k + 1], c2 = scol[k + 2], c3 = scol[k + 3];
                float v0 = bf2f(xb[(size_t)c0 * DF + f]);
                float v1 = bf2f(xb[(size_t)c1 * DF + f]);
                float v2 = bf2f(xb[(size_t)c2 * DF + f]);
                float v3 = bf2f(xb[(size_t)c3 * DF + f]);
                acc += v0; acc += v1; acc += v2; acc += v3;
            }
            for (; k < kend; ++k) acc += bf2f(xb[(size_t)scol[k] * DF + f]);
            if (jp == 0) a0 += acc; else if (jp == 1) a1 += acc;
            else if (jp == 2) a2 += acc; else a3 += acc;
        }
        __syncthreads();
    }

    const float ev = 1.0f + eps[0];
    const int row0 = b << 6;
#pragma unroll
    for (int jp = 0; jp < 4; ++jp) {
        int row = row0 + w + jp * 16;
        if (row < NN) {
            float acc = (jp == 0) ? a0 : (jp == 1) ? a1 : (jp == 2) ? a2 : a3;
            out[(size_t)row * DF + f] = ev * x[(size_t)row * DF + f] + acc;
        }
    }
}

// ---------- MFMA MLP (proven round 9, unchanged) ----------
#define IN_LD 72
#define W1_LD 72
#define W2_LD 136
#define H_LD 136

__global__ __launch_bounds__(256) void k_mlp(float* io,
                                             const float* __restrict__ w1,
                                             const float* __restrict__ b1,
                                             const float* __restrict__ w2,
                                             const float* __restrict__ b2) {
    __shared__ ushort in_s[64 * IN_LD];
    __shared__ ushort w1t_s[128 * W1_LD];
    __shared__ ushort w2t_s[64 * W2_LD];
    __shared__ ushort h_s[4 * 16 * H_LD];

    const int tid = threadIdx.x;
    const int m0 = blockIdx.x * 64;
    const int w = tid >> 6;
    const int lane = tid & 63;
    const int quad = lane >> 4;
    const int r16 = lane & 15;

#pragma unroll
    for (int t = 0; t < 8; ++t) {
        int i4 = t * 256 + tid;
        float4 v = ((const float4*)w1)[i4];
        int idx = i4 * 4;
        int k = idx >> 7, j = idx & 127;
        w1t_s[(j + 0) * W1_LD + k] = f2bf(v.x);
        w1t_s[(j + 1) * W1_LD + k] = f2bf(v.y);
        w1t_s[(j + 2) * W1_LD + k] = f2bf(v.z);
        w1t_s[(j + 3) * W1_LD + k] = f2bf(v.w);
    }
#pragma unroll
    for (int t = 0; t < 8; ++t) {
        int i4 = t * 256 + tid;
        float4 v = ((const float4*)w2)[i4];
        int idx = i4 * 4;
        int j = idx >> 6, c = idx & 63;
        w2t_s[(c + 0) * W2_LD + j] = f2bf(v.x);
        w2t_s[(c + 1) * W2_LD + j] = f2bf(v.y);
        w2t_s[(c + 2) * W2_LD + j] = f2bf(v.z);
        w2t_s[(c + 3) * W2_LD + j] = f2bf(v.w);
    }
#pragma unroll
    for (int t = 0; t < 4; ++t) {
        int i4 = t * 256 + tid;
        int row = i4 >> 4, fq = i4 & 15;
        float4 v = make_float4(0.f, 0.f, 0.f, 0.f);
        if (m0 + row < NN) v = ((const float4*)io)[(size_t)(m0 + row) * 16 + fq];
        ushort4 o;
        o.x = f2bf(v.x); o.y = f2bf(v.y); o.z = f2bf(v.z); o.w = f2bf(v.w);
        *(ushort4*)&in_s[row * IN_LD + fq * 4] = o;
    }
    __syncthreads();

    const ushort* inrow = in_s + (w * 16 + r16) * IN_LD + quad * 8;
    bf16x8 aA = *(const bf16x8*)(inrow);
    bf16x8 aB = *(const bf16x8*)(inrow + 32);

    ushort* hw = h_s + w * 16 * H_LD;

#pragma unroll
    for (int nt = 0; nt < 8; ++nt) {
        const ushort* bp = w1t_s + (nt * 16 + r16) * W1_LD + quad * 8;
        bf16x8 bA = *(const bf16x8*)(bp);
        bf16x8 bB = *(const bf16x8*)(bp + 32);
        f32x4 acc = {0.f, 0.f, 0.f, 0.f};
        acc = __builtin_amdgcn_mfma_f32_16x16x32_bf16(aA, bA, acc, 0, 0, 0);
        acc = __builtin_amdgcn_mfma_f32_16x16x32_bf16(aB, bB, acc, 0, 0, 0);
        float bias = b1[nt * 16 + r16];
#pragma unroll
        for (int reg = 0; reg < 4; ++reg) {
            float hv = fmaxf(acc[reg] + bias, 0.f);
            hw[(quad * 4 + reg) * H_LD + nt * 16 + r16] = f2bf(hv);
        }
    }

    f32x4 acc2[4];
#pragma unroll
    for (int ct = 0; ct < 4; ++ct) acc2[ct] = (f32x4){0.f, 0.f, 0.f, 0.f};
#pragma unroll
    for (int ks = 0; ks < 4; ++ks) {
        bf16x8 a2 = *(const bf16x8*)(hw + r16 * H_LD + quad * 8 + ks * 32);
#pragma unroll
        for (int ct = 0; ct < 4; ++ct) {
            bf16x8 b2f = *(const bf16x8*)(w2t_s + (ct * 16 + r16) * W2_LD + quad * 8 + ks * 32);
            acc2[ct] = __builtin_amdgcn_mfma_f32_16x16x32_bf16(a2, b2f, acc2[ct], 0, 0, 0);
        }
    }
#pragma unroll
    for (int ct = 0; ct < 4; ++ct) {
        int c = ct * 16 + r16;
        float bias = b2[c];
#pragma unroll
        for (int reg = 0; reg < 4; ++reg) {
            int m = m0 + w * 16 + quad * 4 + reg;
            if (m < NN) io[(size_t)m * DF + c] = acc2[ct][reg] + bias;
        }
    }
}

extern "C" void kernel_launch(void* const* d_in, const int* in_sizes, int n_in,
                              void* d_out, int out_size, void* d_ws, size_t ws_size,
                              hipStream_t stream) {
    const float* x   = (const float*)d_in[0];
    const int*   ei  = (const int*)d_in[1];
    const float* w1  = (const float*)d_in[2];
    const float* b1  = (const float*)d_in[3];
    const float* w2  = (const float*)d_in[4];
    const float* b2  = (const float*)d_in[5];
    const float* eps = (const float*)d_in[6];
    float* out = (float*)d_out;

    char* ws = (char*)d_ws;
    int*           cnt    = (int*)(ws + 0);
    int*           start  = (int*)(ws + 4096);
    int*           cursor = (int*)(ws + 8192);
    ushort*        colc   = (ushort*)(ws + 12288);
    unsigned char* rloc   = (unsigned char*)(ws + 3212288);
    ushort*        xb     = (ushort*)(ws + 4812288);

    // cnt zeroed inside k_cast (block 0) -- no memset dispatch
    k_cast<<<NN * DF / 4 / 256, 256, 0, stream>>>(x, xb, cnt);
    k_hist<<<512, 256, 0, stream>>>(ei, cnt);
    k_scan2<<<1, 64, 0, stream>>>(cnt, start, cursor);
    k_part<<<(NE + PB_EDGES - 1) / PB_EDGES, 1024, 0, stream>>>(ei, cursor, colc, rloc);
    k_agg<<<NBK, 1024, 0, stream>>>(x, xb, start, colc, rloc, eps, out);
    k_mlp<<<(NN + 63) / 64, 256, 0, stream>>>(out, w1, b1, w2, b2);
}

// Round 13
// 113.201 us; speedup vs baseline: 1.3494x; 1.0478x over previous
//
#include <hip/hip_runtime.h>

#define NN 50000
#define NE 1600000
#define DF 64
#define DH 128

#define NBK 782           // buckets of 64 rows: bucket = r >> 6
#define PB_EDGES 8192     // edges per k_part block (1024 thr x 8) -> 196 blocks
#define CAPF 4096         // per-chunk edge capacity in k_agg (mean 2046, sd ~45)

// ws layout (bytes):
//   cnt    : int[784]        @ 0         (zeroed by k_cast block 0 each call)
//   start  : int[783]        @ 4096
//   cursor : int[783]        @ 8192
//   colc   : ushort[NE]      @ 12288     (3,200,000 B)
//   rloc   : uchar[NE]       @ 3,212,288 (1,600,000 B)
//   xb     : ushort[NN*DF]   @ 4,812,288 (6,400,000 B)
// total 11,212,288 B (proven budget)

typedef __attribute__((ext_vector_type(8))) short bf16x8;
typedef __attribute__((ext_vector_type(4))) float f32x4;

__device__ __forceinline__ unsigned short f2bf(float f) {
    unsigned u = __float_as_uint(f);
    unsigned r = (u + 0x7FFFu + ((u >> 16) & 1u)) >> 16;  // RNE
    return (unsigned short)r;
}
__device__ __forceinline__ float bf2f(unsigned short h) {
    return __uint_as_float((unsigned)h << 16);
}

// ---------- cast x (f32) -> xb (bf16 raw); block 0 also zeroes cnt ----------
__global__ __launch_bounds__(256) void k_cast(const float* __restrict__ x,
                                              ushort* __restrict__ xb,
                                              int* __restrict__ cnt) {
    if (blockIdx.x == 0) {
        ((int4*)cnt)[threadIdx.x] = make_int4(0, 0, 0, 0);
    }
    unsigned i = blockIdx.x * 256u + threadIdx.x;
    if (i >= NN * DF / 4) return;
    float4 v = ((const float4*)x)[i];
    ushort4 o;
    o.x = f2bf(v.x); o.y = f2bf(v.y); o.z = f2bf(v.z); o.w = f2bf(v.w);
    ((ushort4*)xb)[i] = o;
}

// ---------- bucket histogram (LDS-staged, native int atomics) ----------
__global__ __launch_bounds__(256) void k_hist(const int* __restrict__ ei,
                                              int* __restrict__ cnt) {
    __shared__ int h[784];
    for (int i = threadIdx.x; i < 784; i += 256) h[i] = 0;
    __syncthreads();
    for (unsigned e = blockIdx.x * 256u + threadIdx.x; e < NE; e += 512u * 256u) {
        int r = ei[e];
        int c = ei[NE + e];
        if (r != c) atomicAdd(&h[r >> 6], 1);
    }
    __syncthreads();
    for (int i = threadIdx.x; i < NBK; i += 256)
        if (h[i]) atomicAdd(&cnt[i], h[i]);
}

// ---------- exclusive scan of NBK bucket counts (1 wave) ----------
__global__ __launch_bounds__(64) void k_scan2(const int* __restrict__ cnt,
                                              int* __restrict__ start,
                                              int* __restrict__ cursor) {
    const int lane = threadIdx.x;
    int run = 0;
    for (int base = 0; base < 832; base += 64) {
        int i = base + lane;
        int v = (i < NBK) ? cnt[i] : 0;
        int s = v;
#pragma unroll
        for (int off = 1; off < 64; off <<= 1) {
            int y = __shfl_up(s, off, 64);
            if (lane >= off) s += y;
        }
        int excl = run + s - v;
        if (i < NBK + 1) { start[i] = excl; cursor[i] = excl; }
        run += __shfl(s, 63, 64);
    }
}

// ---------- partition: 8192 edges/block with block-level reservation ----------
__global__ __launch_bounds__(1024) void k_part(const int* __restrict__ ei,
                                               int* __restrict__ cursor,
                                               ushort* __restrict__ colc,
                                               unsigned char* __restrict__ rloc) {
    __shared__ int lhist[784];
    __shared__ int lbase[784];
    const int tid = threadIdx.x;
    const int e0 = blockIdx.x * PB_EDGES;

    for (int i = tid; i < 784; i += 1024) lhist[i] = 0;
    __syncthreads();

    int rr[8], cc[8], bk[8], val[8];
#pragma unroll
    for (int k = 0; k < 8; ++k) {
        int e = e0 + k * 1024 + tid;
        int ok = (e < NE);
        int idx = ok ? e : 0;
        int r = ei[idx];
        int c = ei[NE + idx];
        int v = ok && (r != c);
        rr[k] = r; cc[k] = c; bk[k] = r >> 6; val[k] = v;
        if (v) atomicAdd(&lhist[bk[k]], 1);
    }
    __syncthreads();

    for (int b = tid; b < NBK; b += 1024) {
        int n = lhist[b];
        lbase[b] = (n > 0) ? atomicAdd(&cursor[b], n) : 0;
    }
    __syncthreads();
    for (int i = tid; i < 784; i += 1024) lhist[i] = 0;  // reuse as local cursor
    __syncthreads();

#pragma unroll
    for (int k = 0; k < 8; ++k) {
        if (val[k]) {
            int off = atomicAdd(&lhist[bk[k]], 1);
            int pos = lbase[bk[k]] + off;
            colc[pos] = (unsigned short)cc[k];
            rloc[pos] = (unsigned char)(rr[k] & 63);
        }
    }
}

// ---------- aggregate: one block per 64-row bucket; LDS counting-sort by row,
// register accumulation; 2 features/lane, halves process alternating edges ----------
__global__ __launch_bounds__(1024) void k_agg(const float* __restrict__ x,
                                              const ushort* __restrict__ xb,
                                              const int* __restrict__ start,
                                              const ushort* __restrict__ colc,
                                              const unsigned char* __restrict__ rloc,
                                              const float* __restrict__ eps,
                                              float* __restrict__ out) {
    __shared__ int hist[64];
    __shared__ int rs[65];
    __shared__ int curs[64];
    __shared__ ushort scol[CAPF];    // 8 KB

    const int tid = threadIdx.x;
    const int b = blockIdx.x;
    const int w = tid >> 6;         // wave 0..15
    const int h = (tid >> 5) & 1;   // half: which edge of the pair
    const int fp = tid & 31;        // feature pair -> features 2fp, 2fp+1
    const int s = start[b], e = start[b + 1];

    float sx0 = 0.f, sy0 = 0.f, sx1 = 0.f, sy1 = 0.f;
    float sx2 = 0.f, sy2 = 0.f, sx3 = 0.f, sy3 = 0.f;

    for (int cs0 = s; cs0 < e; cs0 += CAPF) {
        const int m = min(e - cs0, CAPF);

        if (tid < 64) hist[tid] = 0;
        __syncthreads();

        for (int i = tid; i < m; i += 1024)
            atomicAdd(&hist[rloc[cs0 + i]], 1);
        __syncthreads();

        if (tid < 64) {
            int v = hist[tid];
            int p = v;
#pragma unroll
            for (int off = 1; off < 64; off <<= 1) {
                int y = __shfl_up(p, off, 64);
                if (tid >= off) p += y;
            }
            rs[tid] = p - v;
            curs[tid] = p - v;
            if (tid == 63) rs[64] = p;
        }
        __syncthreads();

        for (int i = tid; i < m; i += 1024) {
            int r = rloc[cs0 + i];
            int p = atomicAdd(&curs[r], 1);
            scol[p] = colc[cs0 + i];
        }
        __syncthreads();

        // wave w owns rows w, w+16, w+32, w+48; halves h=0/1 take alternating
        // edges; each lane covers features 2fp,2fp+1 via one uint load.
#pragma unroll
        for (int jp = 0; jp < 4; ++jp) {
            const int rl = w + jp * 16;
            int k = rs[rl];
            const int kend = rs[rl + 1];
            float sx = 0.f, sy = 0.f;
            for (; k + 16 <= kend; k += 16) {
                int c0 = scol[k + 0 + h],  c1 = scol[k + 2 + h];
                int c2 = scol[k + 4 + h],  c3 = scol[k + 6 + h];
                int c4 = scol[k + 8 + h],  c5 = scol[k + 10 + h];
                int c6 = scol[k + 12 + h], c7 = scol[k + 14 + h];
                unsigned u0 = *(const unsigned*)(xb + (size_t)c0 * DF + 2 * fp);
                unsigned u1 = *(const unsigned*)(xb + (size_t)c1 * DF + 2 * fp);
                unsigned u2 = *(const unsigned*)(xb + (size_t)c2 * DF + 2 * fp);
                unsigned u3 = *(const unsigned*)(xb + (size_t)c3 * DF + 2 * fp);
                unsigned u4 = *(const unsigned*)(xb + (size_t)c4 * DF + 2 * fp);
                unsigned u5 = *(const unsigned*)(xb + (size_t)c5 * DF + 2 * fp);
                unsigned u6 = *(const unsigned*)(xb + (size_t)c6 * DF + 2 * fp);
                unsigned u7 = *(const unsigned*)(xb + (size_t)c7 * DF + 2 * fp);
                sx += __uint_as_float(u0 << 16); sy += __uint_as_float(u0 & 0xffff0000u);
                sx += __uint_as_float(u1 << 16); sy += __uint_as_float(u1 & 0xffff0000u);
                sx += __uint_as_float(u2 << 16); sy += __uint_as_float(u2 & 0xffff0000u);
                sx += __uint_as_float(u3 << 16); sy += __uint_as_float(u3 & 0xffff0000u);
                sx += __uint_as_float(u4 << 16); sy += __uint_as_float(u4 & 0xffff0000u);
                sx += __uint_as_float(u5 << 16); sy += __uint_as_float(u5 & 0xffff0000u);
                sx += __uint_as_float(u6 << 16); sy += __uint_as_float(u6 & 0xffff0000u);
                sx += __uint_as_float(u7 << 16); sy += __uint_as_float(u7 & 0xffff0000u);
            }
            for (; k + 2 <= kend; k += 2) {
                int c = scol[k + h];
                unsigned u = *(const unsigned*)(xb + (size_t)c * DF + 2 * fp);
                sx += __uint_as_float(u << 16);
                sy += __uint_as_float(u & 0xffff0000u);
            }
            if (k < kend && h == 0) {   // odd leftover edge: h=0 half takes it
                int c = scol[k];
                unsigned u = *(const unsigned*)(xb + (size_t)c * DF + 2 * fp);
                sx += __uint_as_float(u << 16);
                sy += __uint_as_float(u & 0xffff0000u);
            }
            if (jp == 0) { sx0 += sx; sy0 += sy; }
            else if (jp == 1) { sx1 += sx; sy1 += sy; }
            else if (jp == 2) { sx2 += sx; sy2 += sy; }
            else { sx3 += sx; sy3 += sy; }
        }
        __syncthreads();
    }

    // combine halves, write out = (1+eps)*x + agg (h=0 lanes, float2 coalesced)
    const float ev = 1.0f + eps[0];
    const int row0 = b << 6;
#pragma unroll
    for (int jp = 0; jp < 4; ++jp) {
        float sx = (jp == 0) ? sx0 : (jp == 1) ? sx1 : (jp == 2) ? sx2 : sx3;
        float sy = (jp == 0) ? sy0 : (jp == 1) ? sy1 : (jp == 2) ? sy2 : sy3;
        float tx = sx + __shfl_xor(sx, 32, 64);
        float ty = sy + __shfl_xor(sy, 32, 64);
        const int row = row0 + w + jp * 16;
        if (h == 0 && row < NN) {
            float2 xv = *(const float2*)(x + (size_t)row * DF + 2 * fp);
            float2 o;
            o.x = ev * xv.x + tx;
            o.y = ev * xv.y + ty;
            *(float2*)(out + (size_t)row * DF + 2 * fp) = o;
        }
    }
}

// ---------- MFMA MLP (proven round 9, unchanged) ----------
#define IN_LD 72
#define W1_LD 72
#define W2_LD 136
#define H_LD 136

__global__ __launch_bounds__(256) void k_mlp(float* io,
                                             const float* __restrict__ w1,
                                             const float* __restrict__ b1,
                                             const float* __restrict__ w2,
                                             const float* __restrict__ b2) {
    __shared__ ushort in_s[64 * IN_LD];
    __shared__ ushort w1t_s[128 * W1_LD];
    __shared__ ushort w2t_s[64 * W2_LD];
    __shared__ ushort h_s[4 * 16 * H_LD];

    const int tid = threadIdx.x;
    const int m0 = blockIdx.x * 64;
    const int w = tid >> 6;
    const int lane = tid & 63;
    const int quad = lane >> 4;
    const int r16 = lane & 15;

#pragma unroll
    for (int t = 0; t < 8; ++t) {
        int i4 = t * 256 + tid;
        float4 v = ((const float4*)w1)[i4];
        int idx = i4 * 4;
        int k = idx >> 7, j = idx & 127;
        w1t_s[(j + 0) * W1_LD + k] = f2bf(v.x);
        w1t_s[(j + 1) * W1_LD + k] = f2bf(v.y);
        w1t_s[(j + 2) * W1_LD + k] = f2bf(v.z);
        w1t_s[(j + 3) * W1_LD + k] = f2bf(v.w);
    }
#pragma unroll
    for (int t = 0; t < 8; ++t) {
        int i4 = t * 256 + tid;
        float4 v = ((const float4*)w2)[i4];
        int idx = i4 * 4;
        int j = idx >> 6, c = idx & 63;
        w2t_s[(c + 0) * W2_LD + j] = f2bf(v.x);
        w2t_s[(c + 1) * W2_LD + j] = f2bf(v.y);
        w2t_s[(c + 2) * W2_LD + j] = f2bf(v.z);
        w2t_s[(c + 3) * W2_LD + j] = f2bf(v.w);
    }
#pragma unroll
    for (int t = 0; t < 4; ++t) {
        int i4 = t * 256 + tid;
        int row = i4 >> 4, fq = i4 & 15;
        float4 v = make_float4(0.f, 0.f, 0.f, 0.f);
        if (m0 + row < NN) v = ((const float4*)io)[(size_t)(m0 + row) * 16 + fq];
        ushort4 o;
        o.x = f2bf(v.x); o.y = f2bf(v.y); o.z = f2bf(v.z); o.w = f2bf(v.w);
        *(ushort4*)&in_s[row * IN_LD + fq * 4] = o;
    }
    __syncthreads();

    const ushort* inrow = in_s + (w * 16 + r16) * IN_LD + quad * 8;
    bf16x8 aA = *(const bf16x8*)(inrow);
    bf16x8 aB = *(const bf16x8*)(inrow + 32);

    ushort* hw = h_s + w * 16 * H_LD;

#pragma unroll
    for (int nt = 0; nt < 8; ++nt) {
        const ushort* bp = w1t_s + (nt * 16 + r16) * W1_LD + quad * 8;
        bf16x8 bA = *(const bf16x8*)(bp);
        bf16x8 bB = *(const bf16x8*)(bp + 32);
        f32x4 acc = {0.f, 0.f, 0.f, 0.f};
        acc = __builtin_amdgcn_mfma_f32_16x16x32_bf16(aA, bA, acc, 0, 0, 0);
        acc = __builtin_amdgcn_mfma_f32_16x16x32_bf16(aB, bB, acc, 0, 0, 0);
        float bias = b1[nt * 16 + r16];
#pragma unroll
        for (int reg = 0; reg < 4; ++reg) {
            float hv = fmaxf(acc[reg] + bias, 0.f);
            hw[(quad * 4 + reg) * H_LD + nt * 16 + r16] = f2bf(hv);
        }
    }

    f32x4 acc2[4];
#pragma unroll
    for (int ct = 0; ct < 4; ++ct) acc2[ct] = (f32x4){0.f, 0.f, 0.f, 0.f};
#pragma unroll
    for (int ks = 0; ks < 4; ++ks) {
        bf16x8 a2 = *(const bf16x8*)(hw + r16 * H_LD + quad * 8 + ks * 32);
#pragma unroll
        for (int ct = 0; ct < 4; ++ct) {
            bf16x8 b2f = *(const bf16x8*)(w2t_s + (ct * 16 + r16) * W2_LD + quad * 8 + ks * 32);
            acc2[ct] = __builtin_amdgcn_mfma_f32_16x16x32_bf16(a2, b2f, acc2[ct], 0, 0, 0);
        }
    }
#pragma unroll
    for (int ct = 0; ct < 4; ++ct) {
        int c = ct * 16 + r16;
        float bias = b2[c];
#pragma unroll
        for (int reg = 0; reg < 4; ++reg) {
            int m = m0 + w * 16 + quad * 4 + reg;
            if (m < NN) io[(size_t)m * DF + c] = acc2[ct][reg] + bias;
        }
    }
}

extern "C" void kernel_launch(void* const* d_in, const int* in_sizes, int n_in,
                              void* d_out, int out_size, void* d_ws, size_t ws_size,
                              hipStream_t stream) {
    const float* x   = (const float*)d_in[0];
    const int*   ei  = (const int*)d_in[1];
    const float* w1  = (const float*)d_in[2];
    const float* b1  = (const float*)d_in[3];
    const float* w2  = (const float*)d_in[4];
    const float* b2  = (const float*)d_in[5];
    const float* eps = (const float*)d_in[6];
    float* out = (float*)d_out;

    char* ws = (char*)d_ws;
    int*           cnt    = (int*)(ws + 0);
    int*           start  = (int*)(ws + 4096);
    int*           cursor = (int*)(ws + 8192);
    ushort*        colc   = (ushort*)(ws + 12288);
    unsigned char* rloc   = (unsigned char*)(ws + 3212288);
    ushort*        xb     = (ushort*)(ws + 4812288);

    // cnt zeroed inside k_cast (block 0) -- no memset dispatch
    k_cast<<<NN * DF / 4 / 256, 256, 0, stream>>>(x, xb, cnt);
    k_hist<<<512, 256, 0, stream>>>(ei, cnt);
    k_scan2<<<1, 64, 0, stream>>>(cnt, start, cursor);
    k_part<<<(NE + PB_EDGES - 1) / PB_EDGES, 1024, 0, stream>>>(ei, cursor, colc, rloc);
    k_agg<<<NBK, 1024, 0, stream>>>(x, xb, start, colc, rloc, eps, out);
    k_mlp<<<(NN + 63) / 64, 256, 0, stream>>>(out, w1, b1, w2, b2);
}